// Round 6
// baseline (467.489 us; speedup 1.0000x reference)
//
#include <hip/hip_runtime.h>
#include <stdint.h>
#include <stddef.h>

// ---------------------------------------------------------------------------
// BayesianDTW forward on MI355X — R12: deferred-log2 pair representation.
// Base: R11 (passed, 350us, absmax 8.0). Evidence: R9/R10/R11 all ~345us
// regardless of staging path, output path, lag steps, instruction count;
// VALUBusy 4.2-4.9% matches 2.4GHz + ~94% per-step stall => the serial
// chain's FOUR transcendentals (exp2,log2,exp2,log2) are the bottleneck.
//
// R12: carry each cell as u = p + log2(q), q in [1,~6):
//   lse3(u1,u2,u3) pair form: m = max3(p1,p2,p3);
//   q' = q1*exp2(p1-m) + q2*exp2(p2-m) + q3*exp2(p3-m);  p' = w*log2e + m.
//   exp2 args <= 0 ALWAYS (max over the same p's) -> NaN-free, exactly the
//   R3-proven lse3 discipline. NO log2 on the carried chain; B-cell's max3
//   uses pAn = w+m1 (ready 2 ops after m1) so B's exp2s run concurrent
//   with A's => ONE exp2 of serial depth per step (was 4 transcendentals).
//   log2 appears only in the off-chain output store (p + log2(q))*ln2.
//   Per-step renorm (exponent fold: p += e(q); q *= 2^-e) keeps q in [1,2);
//   pre-renorm bound qA'<=6, qB'<=10 < 16 -> f32-exact, no drift tracking.
//   Boundary cells: pair (NEG2, 1) == log2-domain NEG2 exactly.
// Everything else (W reg-ring, CH=8 boundaries, flag protocol, lds_o flush,
// loop split prologue/middle/epilogue): R11-VERBATIM.
// ---------------------------------------------------------------------------

#define NBATCH  32
#define NA      512
#define NB      1024
#define NSTRIPE 8
#define SW      128          // cols per stripe
#define CH      8            // rows per chunk
#define NCHUNK  (NA / CH)    // 64
#define LSTR    128          // lds_o row stride (floats)
#define OROWS   513
#define OCOLS   1025
#define FSTRIDE 32           // flag padding: 128 B

#define NEGV    (-1e20f)
#define LOG2E   (1.4426950408889634f)
#define LN2     (0.6931471805599453f)
#define NEG2    (-1.4426950408889634e20f)   // NEGV in log2 units
#define FLAGTAG 0x5A000000u

#define EXP2F(x) __builtin_amdgcn_exp2f(x)   // v_exp_f32: 2^x
#define LOG2F(x) __builtin_amdgcn_logf(x)    // v_log_f32: log2(x)

__device__ __forceinline__ float rdlane(float v, int l) {
    return __int_as_float(__builtin_amdgcn_readlane(__float_as_int(v), l));
}

// lane i <- lane i-1 across the full wave, pure VALU:
// DPP row_shr:1 (16-lane rows) + readlane patches at lanes 16/32/48.
__device__ __forceinline__ float lane_shr1(float x, int lane) {
    int xi  = __float_as_int(x);
    int shr = __builtin_amdgcn_update_dpp(0, xi, 0x111, 0xf, 0xf, true);
    float v = __int_as_float(shr);
    float a15 = rdlane(x, 15), a31 = rdlane(x, 31), a47 = rdlane(x, 47);
    v = (lane == 16) ? a15 : v;
    v = (lane == 32) ? a31 : v;
    v = (lane == 48) ? a47 : v;
    return v;
}

__device__ __forceinline__ unsigned int ld_flag(unsigned int* fp) {
    return __hip_atomic_load(fp, __ATOMIC_RELAXED, __HIP_MEMORY_SCOPE_AGENT);
}
__device__ __forceinline__ void st_flag(unsigned int* fp, unsigned int v) {
    __hip_atomic_store(fp, v, __ATOMIC_RELAXED, __HIP_MEMORY_SCOPE_AGENT);
}
__device__ __forceinline__ float ld_edge(const float* p) {
    return __hip_atomic_load((float*)p, __ATOMIC_RELAXED, __HIP_MEMORY_SCOPE_AGENT);
}
__device__ __forceinline__ void st_edge(float* p, float v) {
    __hip_atomic_store(p, v, __ATOMIC_RELAXED, __HIP_MEMORY_SCOPE_AGENT);
}

__device__ __forceinline__ void wait_flag(unsigned int* fp, unsigned int need) {
    for (int k = 0; k < (1 << 22); ++k) {
        unsigned int v = ld_flag(fp);
        if ((v >> 24) == 0x5Au && (v & 0x00FFFFFFu) >= need) break;
    }
    asm volatile("" ::: "memory");
}

__global__ __launch_bounds__(64, 1)
void dtw_pipe(const float* __restrict__ W, float* __restrict__ out,
              unsigned int* __restrict__ flags)
{
    __shared__ float lds_o[128 * LSTR];   // output ring (ln units, final)

    const int lane = (int)threadIdx.x;
    const int bid  = (int)blockIdx.x;             // s*32 + b
    const int b    = bid & (NBATCH - 1);
    const int s    = bid >> 5;

    const float*  Wb  = W + ((size_t)b * NA) * NB + s * SW;
    float*        ob  = out + (size_t)b * OROWS * OCOLS;
    unsigned int* fmy = flags + (size_t)bid * FSTRIDE;
    unsigned int* fup = flags + (size_t)(bid - NBATCH) * FSTRIDE;

    // ---- boundary cells of output (final values; nobody reads these) ----
    ob[s * SW + 1 + lane]      = NEGV;
    ob[s * SW + 1 + 64 + lane] = NEGV;
    if (s == 0) {
        if (lane == 0) ob[0] = 0.0f;
        for (int r = lane; r < NA; r += 64)
            ob[(size_t)(r + 1) * OCOLS] = NEGV;
    }

    // ---- W register ring: prime rows 0..3 (clamped; r(t)=t-lane) ----
    float2 wr[4];
    #pragma unroll
    for (int k = 0; k < 4; ++k) {
        int rowc = k - lane;
        rowc = rowc < 0 ? 0 : rowc;
        wr[k] = *(const float2*)&Wb[(size_t)rowc * NB + 2 * lane];
    }

    // ---- edge prefetch (log2 units; lanes 0..7 hold 8 rows each) ----
    float evcur = -1e30f, evnxt = -1e30f, lres = -1e30f;
    if (s > 0) {
        wait_flag(fup, 1u);
        if (lane < CH)
            evcur = ld_edge(&ob[(size_t)(1 + lane) * OCOLS + s * SW]) * LOG2E;
        wait_flag(fup, 2u);
        if (lane < CH)
            evnxt = ld_edge(&ob[(size_t)(CH + 1 + lane) * OCOLS + s * SW]) * LOG2E;
        wait_flag(fup, 3u);
        if (lane < CH)
            lres  = ld_edge(&ob[(size_t)(2 * CH + 1 + lane) * OCOLS + s * SW]) * LOG2E;
    }

    asm volatile("s_waitcnt vmcnt(0)" ::: "memory");   // primes + edges done

    // ---- systolic state: deferred-log2 pairs (u = p + log2 q) ----
    float pA = NEG2, qA = 1.0f;   // uA(prev) = topA
    float pB = NEG2, qB = 1.0f;   // uB(prev) = topB
    float tlp = NEG2, tlq = 1.0f; // tl = mu[i-1, jA-1]
    float shp = NEG2, shq = 1.0f; // left neighbor's uB pair
    float ev_im1 = (s == 0) ? 0.0f : NEG2;  // lane0 topleft (p; q=1)
    unsigned int fpoll = 0;

    auto stepc = [&](int m, int tt, bool GATE, bool GNA) {
        const int t = 8 * m + tt;
        const int r = t - lane;
        if (tt == 1 && s > 0) fpoll = ld_flag(fup);      // hidden poll
        const float2 wv = wr[tt & 3];                    // copy, then refill
        {   // issue W load for row r+4 into the same slot
            int rowc = r + 4;
            rowc = rowc < 0 ? 0 : (rowc > NA - 1 ? NA - 1 : rowc);
            wr[tt & 3] = *(const float2*)&Wb[(size_t)rowc * NB + 2 * lane];
        }
        const float ev_i = rdlane(evcur, tt);
        const bool l0 = (lane == 0);
        const float lfp = l0 ? ev_i   : shp;   // lf pair
        const float lfq = l0 ? 1.0f   : shq;
        const float tpp = l0 ? ev_im1 : tlp;   // tl pair
        const float tpq = l0 ? 1.0f   : tlq;
        // ---- A-cell: uA = wx + lse3(topA, lf, tl), pair form ----
        const float m1  = fmaxf(fmaxf(pA, lfp), tpp);
        const float qAn = qA  * EXP2F(pA  - m1)
                        + lfq * EXP2F(lfp - m1)
                        + tpq * EXP2F(tpp - m1);
        const float pAn = fmaf(wv.x, LOG2E, m1);
        // ---- B-cell: uB = wy + lse3(topB, uA, topA) ----
        // m2 inputs ready 2 ops after m1 -> B's exp2s overlap A's.
        const float m2  = fmaxf(fmaxf(pB, pAn), pA);
        const float qBn = qB  * EXP2F(pB  - m2)
                        + qAn * EXP2F(pAn - m2)
                        + qA  * EXP2F(pA  - m2);
        const float pBn = fmaf(wv.y, LOG2E, m2);
        bool db = true;
        if (GATE) db = (r >= 0);
        if (GNA)  db = (r < NA);
        if (db) {   // off-chain store: ln value = (p + log2 q) * ln2
            const float lnA = (pAn + LOG2F(qAn)) * LN2;
            const float lnB = (pBn + LOG2F(qBn)) * LN2;
            *(float2*)&lds_o[(r & 127) * LSTR + 2 * lane]
                = make_float2(lnA, lnB);
        }
        // ---- renorm pairs: fold exponent of q into p (q -> [1,2)) ----
        float pAr = pAn, qAr, pBr = pBn, qBr;
        {   const int qi = __float_as_int(qAn);
            const int e  = ((qi >> 23) & 0xff) - 127;     // 0..2 (qAn<8)
            pAr += (float)e;
            qAr  = __int_as_float(qi - (e << 23));
        }
        {   const int qi = __float_as_int(qBn);
            const int e  = ((qi >> 23) & 0xff) - 127;     // 0..3 (qBn<16)
            pBr += (float)e;
            qBr  = __int_as_float(qi - (e << 23));
        }
        if (GATE) {
            const bool on = (r >= 0);
            pA  = on ? pAr : NEG2;  qA  = on ? qAr : 1.0f;
            pB  = on ? pBr : NEG2;  qB  = on ? qBr : 1.0f;
            tlp = on ? lfp : NEG2;  tlq = on ? lfq : 1.0f;
        } else {
            pA = pAr; qA = qAr; pB = pBr; qB = qBr;
            tlp = lfp; tlq = lfq;
        }
        ev_im1 = ev_i;
        // shift RAW (renormed, pre-gate) uB pair to right neighbor; the
        // consumer lane is active one step later than producer -> valid.
        shp = lane_shr1(pBr, lane);
        shq = lane_shr1(qBr, lane);
    };

    auto boundary = [&](int m) {
        const int f = m - 8;                  // chunk fully complete (skew 63)
        // 1) agent-scope edge-column dup for chunk f
        if (s < NSTRIPE - 1 && f >= 0 && lane < CH) {
            const int rw = (f << 3) + lane;
            const float evl = lds_o[(rw & 127) * LSTR + 127];
            st_edge(ob + (size_t)(rw + 1) * OCOLS + (s + 1) * SW, evl);
        }
        // 2) vmcnt(4): everything except the 4 newest vmem ops retired ->
        //    dup(f-1) from boundary m-1 drained -> publish v=f.
        asm volatile("s_waitcnt vmcnt(4)" ::: "memory");
        if (s < NSTRIPE - 1 && f >= 1 && lane == 0)
            st_flag(fmy, FLAGTAG + (unsigned)f);
        // 3) coalesced flush of chunk f
        if (f >= 0) {
            #pragma unroll
            for (int rr = 0; rr < CH; ++rr) {
                const int rw = (f << 3) + rr;
                const float v0 = lds_o[(rw & 127) * LSTR + lane];
                const float v1 = lds_o[(rw & 127) * LSTR + 64 + lane];
                float* orow = ob + (size_t)(rw + 1) * OCOLS + s * SW + 1;
                orow[lane]      = v0;
                orow[64 + lane] = v1;
            }
        }
        // 4) rotate edge regs; load chunk m+3 (need m+4, polled at tt==1)
        evcur = evnxt; evnxt = lres;
        const int c = m + 3;
        if (s > 0 && c < NCHUNK) {
            const unsigned need = (unsigned)(m + 4);
            if (!((fpoll >> 24) == 0x5Au && (fpoll & 0x00FFFFFFu) >= need))
                wait_flag(fup, need);
            lres = -1e30f;
            if (lane < CH)
                lres = ld_edge(&ob[(size_t)((c << 3) + 1 + lane) * OCOLS + s * SW])
                       * LOG2E;
        }
    };

    // ---- prologue: m=0..7 (some lanes r<0; full gating) ----
    for (int m = 0; m < 8; ++m) {
        #pragma unroll
        for (int tt = 0; tt < 8; ++tt) stepc(m, tt, true, false);
        boundary(m);
    }
    // ---- middle: m=8..63 (every lane 0<=r<NA; no gates) ----
    for (int m = 8; m < 64; ++m) {
        #pragma unroll
        for (int tt = 0; tt < 8; ++tt) stepc(m, tt, false, false);
        boundary(m);
    }
    // ---- epilogue: m=64..70 (store guard only) ----
    for (int m = 64; m < 71; ++m) {
        #pragma unroll
        for (int tt = 0; tt < 8; ++tt) stepc(m, tt, false, true);
        boundary(m);
    }
    // tail steps t = 568..574 (lane 63 finishes row 511 at t=574)
    #pragma unroll
    for (int tt = 0; tt < 7; ++tt) stepc(71, tt, false, true);

    // ---- final: chunk 63 ----
    {
        const int f = NCHUNK - 1;
        if (s < NSTRIPE - 1 && lane < CH) {
            const int rw = (f << 3) + lane;
            const float evl = lds_o[(rw & 127) * LSTR + 127];
            st_edge(ob + (size_t)(rw + 1) * OCOLS + (s + 1) * SW, evl);
        }
        asm volatile("s_waitcnt vmcnt(1)" ::: "memory");
        if (s < NSTRIPE - 1 && lane == 0)
            st_flag(fmy, FLAGTAG + (unsigned)f);          // chunks <= 62
        #pragma unroll
        for (int rr = 0; rr < CH; ++rr) {
            const int rw = (f << 3) + rr;
            const float v0 = lds_o[(rw & 127) * LSTR + lane];
            const float v1 = lds_o[(rw & 127) * LSTR + 64 + lane];
            float* orow = ob + (size_t)(rw + 1) * OCOLS + s * SW + 1;
            orow[lane]      = v0;
            orow[64 + lane] = v1;
        }
        asm volatile("s_waitcnt vmcnt(0)" ::: "memory");
        if (s < NSTRIPE - 1 && lane == 0)
            st_flag(fmy, FLAGTAG + (unsigned)NCHUNK);     // all 64 chunks
    }
}

extern "C" void kernel_launch(void* const* d_in, const int* in_sizes, int n_in,
                              void* d_out, int out_size, void* d_ws, size_t ws_size,
                              hipStream_t stream) {
    const float*  W     = (const float*)d_in[0];
    float*        out   = (float*)d_out;
    unsigned int* flags = (unsigned int*)d_ws;
    (void)in_sizes; (void)n_in; (void)out_size; (void)ws_size;
    hipLaunchKernelGGL(dtw_pipe, dim3(NBATCH * NSTRIPE), dim3(64), 0, stream,
                       W, out, flags);
}